// Round 1
// baseline (187.319 us; speedup 1.0000x reference)
//
#include <hip/hip_runtime.h>
#include <math.h>

#define BB 4
#define HH 64
#define WW 64
#define CC 256
#define NN 4096   // H*W
#define MM 1024   // (H/2)*(W/2)
#define LN_EPS 1e-6f
#define SLF (0.17677669529663687f * 1.4426950408889634f)

typedef __attribute__((ext_vector_type(8)))  short short8;
typedef __attribute__((ext_vector_type(16))) float f32x16;

__device__ __forceinline__ ushort f2bf(float f) {
  unsigned u = __builtin_bit_cast(unsigned, f);
  u += 0x7fffu + ((u >> 16) & 1u);   // RNE
  return (ushort)(u >> 16);
}
__device__ __forceinline__ float bf2f(ushort h) {
  unsigned u = ((unsigned)h) << 16;
  return __builtin_bit_cast(float, u);
}
#if __has_builtin(__builtin_amdgcn_exp2f)
#define EXP2F(x) __builtin_amdgcn_exp2f(x)
#else
#define EXP2F(x) exp2f(x)
#endif

// ---------------------------------------------------------------------------
// 1) FUSED front end: blocks [0,4096): srln; blocks [4096,4608): dwconv
__global__ __launch_bounds__(256) void pre_fused(
    const float* __restrict__ x, const float* __restrict__ dw_w,
    const float* __restrict__ dw_b, const float* __restrict__ sr_w,
    const float* __restrict__ ln_g, const float* __restrict__ ln_b,
    ushort* __restrict__ q1b, ushort* __restrict__ xsr) {
  int bid = blockIdx.x;
  int c = threadIdx.x;
  if (bid < 4096) {
    int b = bid >> 10, m = bid & 1023;
    int my = m >> 5, mx = m & 31;
    const float* xb = x + (size_t)b * NN * CC + c;
    float acc = 0.f;
#pragma unroll
    for (int dy = 0; dy < 3; ++dy) {
      int iy = 2 * my + dy - 1;
      if (iy < 0 || iy >= HH) continue;
#pragma unroll
      for (int dx = 0; dx < 3; ++dx) {
        int ix = 2 * mx + dx - 1;
        if (ix < 0 || ix >= WW) continue;
        acc += xb[(size_t)(iy * WW + ix) * CC] * sr_w[c * 9 + dy * 3 + dx];
      }
    }
    float v1 = acc, v2 = acc * acc;
#pragma unroll
    for (int s = 1; s < 64; s <<= 1) {
      v1 += __shfl_xor(v1, s);
      v2 += __shfl_xor(v2, s);
    }
    __shared__ float r1[4], r2[4];
    int lane = c & 63, wv = c >> 6;
    if (lane == 0) { r1[wv] = v1; r2[wv] = v2; }
    __syncthreads();
    float s1 = r1[0] + r1[1] + r1[2] + r1[3];
    float s2 = r2[0] + r2[1] + r2[2] + r2[3];
    float mu = s1 * (1.f / 256.f);
    float var = s2 * (1.f / 256.f) - mu * mu;
    float yv = (acc - mu) * rsqrtf(var + LN_EPS) * ln_g[c] + ln_b[c];
    xsr[((size_t)b * MM + m) * CC + c] = f2bf(yv);
  } else {
    int id = bid - 4096;
    int b = id >> 7, yy = id & 127;
    int y = yy >> 1, hf = yy & 1;
    float wr[9];
#pragma unroll
    for (int i = 0; i < 9; ++i) wr[i] = dw_w[c * 9 + i];
    float bi = dw_b[c];
    const float* xb = x + (size_t)b * NN * CC + c;
    int x0 = hf * 32;
    bool okT = (y > 0), okB = (y < 63);
    float a0, a1, a2, b0, b1, b2;
    if (x0 == 0) {
      a0 = a1 = a2 = 0.f;
    } else {
      a0 = okT ? xb[(size_t)((y - 1) * 64 + x0 - 1) * CC] : 0.f;
      a1 = xb[(size_t)(y * 64 + x0 - 1) * CC];
      a2 = okB ? xb[(size_t)((y + 1) * 64 + x0 - 1) * CC] : 0.f;
    }
    b0 = okT ? xb[(size_t)((y - 1) * 64 + x0) * CC] : 0.f;
    b1 = xb[(size_t)(y * 64 + x0) * CC];
    b2 = okB ? xb[(size_t)((y + 1) * 64 + x0) * CC] : 0.f;
    ushort* ob = q1b + ((size_t)b * NN + y * 64) * CC + c;
#pragma unroll 8
    for (int xx = x0; xx < x0 + 32; ++xx) {
      float c0v, c1v, c2v;
      if (xx < 63) {
        c0v = okT ? xb[(size_t)((y - 1) * 64 + xx + 1) * CC] : 0.f;
        c1v = xb[(size_t)(y * 64 + xx + 1) * CC];
        c2v = okB ? xb[(size_t)((y + 1) * 64 + xx + 1) * CC] : 0.f;
      } else {
        c0v = c1v = c2v = 0.f;
      }
      float acc = bi;
      acc += a0 * wr[0] + b0 * wr[1] + c0v * wr[2];
      acc += a1 * wr[3] + b1 * wr[4] + c1v * wr[5];
      acc += a2 * wr[6] + b2 * wr[7] + c2v * wr[8];
      ob[(size_t)xx * CC] = f2bf(acc);
      a0 = b0; a1 = b1; a2 = b2;
      b0 = c0v; b1 = c1v; b2 = c2v;
    }
  }
}

// ---------------------------------------------------------------------------
// 2) FUSED q-GEMM + kv-GEMM. 64x64 tiles, double-buffered single-barrier.
__global__ __launch_bounds__(256) void gemm_qkv(
    const ushort* __restrict__ q1b, const ushort* __restrict__ xsr,
    const float* __restrict__ pw_w, const float* __restrict__ pw_b,
    const float* __restrict__ kv_w, const float* __restrict__ kv_b,
    ushort* __restrict__ qB, ushort* __restrict__ kB,
    ushort* __restrict__ vT) {
  __shared__ ushort smem[2][128 * 40];
  int bid = blockIdx.x;
  bool is0 = bid < 1024;
  const ushort* A;
  const float* W;
  const float* bias;
  int r0, c0;
  if (is0) {
    A = q1b; W = pw_w; bias = pw_b;
    r0 = (bid >> 2) * 64; c0 = (bid & 3) * 64;
  } else {
    int sid = bid - 1024;
    A = xsr; W = kv_w; bias = kv_b;
    r0 = (sid >> 3) * 64; c0 = (sid & 7) * 64;
  }
  const bool vmode = (!is0) && (c0 >= 256);

  int t = threadIdx.x;
  int lane = t & 63, w = t >> 6;
  int l31 = lane & 31, half = lane >> 5;
  int wr = w >> 1, wc = w & 1;
  int rowA = t >> 2, kq = (t & 3) * 8;

  f32x16 acc;
#pragma unroll
  for (int i = 0; i < 16; ++i) acc[i] = 0.f;

  short8 ra;
  float4 rw0, rw1;
  auto prefetch = [&](int kc) {
    ra = *(const short8*)&A[(size_t)(r0 + rowA) * 256 + kc + kq];
    const float* wp = &W[(size_t)(c0 + rowA) * 256 + kc + kq];
    rw0 = *(const float4*)wp;
    rw1 = *(const float4*)(wp + 4);
  };
  auto store = [&](ushort* buf) {
    *(short8*)&buf[rowA * 40 + kq] = ra;
    float vals[8] = {rw0.x, rw0.y, rw0.z, rw0.w, rw1.x, rw1.y, rw1.z, rw1.w};
    short8 hi;
#pragma unroll
    for (int j = 0; j < 8; ++j) hi[j] = (short)f2bf(vals[j]);
    *(short8*)&buf[64 * 40 + rowA * 40 + kq] = hi;
  };

  prefetch(0);
  store(smem[0]);
  __syncthreads();
  for (int i = 0; i < 8; ++i) {
    ushort* cur = smem[i & 1];
    ushort* nxt = smem[(i & 1) ^ 1];
    if (i < 7) prefetch((i + 1) * 32);
#pragma unroll
    for (int ks = 0; ks < 2; ++ks) {
      short8 af = *(const short8*)&cur[(wr * 32 + l31) * 40 + ks * 16 + half * 8];
      short8 wf = *(const short8*)&cur[64 * 40 + (wc * 32 + l31) * 40 + ks * 16 + half * 8];
      if (vmode)
        acc = __builtin_amdgcn_mfma_f32_32x32x16_bf16(wf, af, acc, 0, 0, 0);
      else
        acc = __builtin_amdgcn_mfma_f32_32x32x16_bf16(af, wf, acc, 0, 0, 0);
    }
    if (i < 7) store(nxt);
    __syncthreads();
  }

#pragma unroll
  for (int i = 0; i < 16; ++i) {
    int rl = (i & 3) + 8 * (i >> 2) + 4 * half;
    if (is0) {
      int r = r0 + wr * 32 + rl;
      int c = c0 + wc * 32 + l31;
      int b = r >> 12, n = r & 4095;
      int h = c >> 5, d = c & 31;
      qB[((size_t)(b * 8 + h) * NN + n) * 32 + d] =
          f2bf((acc[i] + bias[c]) * SLF);
    } else if (!vmode) {
      int r = r0 + wr * 32 + rl;
      int c = c0 + wc * 32 + l31;
      int b = r >> 10, m = r & 1023;
      int h = c >> 5, d = c & 31;
      kB[((size_t)(b * 8 + h) * MM + m) * 32 + d] = f2bf(acc[i] + bias[c]);
    } else {
      int c = c0 + wc * 32 + rl;
      int r = r0 + wr * 32 + l31;
      int b = r >> 10, m = r & 1023;
      int cv = c - 256;
      int h = cv >> 5, d = cv & 31;
      vT[((size_t)(b * 8 + h) * 32 + d) * MM + m] = f2bf(acc[i] + bias[c]);
    }
  }
}

// ---------------------------------------------------------------------------
// 3) MFMA flash attention, BARRIER-FREE main loop.
//    K/V per (b,h) is 128 KB and shared by 32 blocks -> L2-resident; load
//    MFMA fragments directly from global instead of LDS-staging (removes
//    all 16 __syncthreads per block; warps fully independent). pB (P tiles)
//    stays per-warp in LDS (B-operand layout requires the shuffle through
//    memory); same-wave RAW handled by compiler lgkmcnt. Math unchanged:
//    no online max (scores bounded in log2 domain), P = exp2(st),
//    denominator via MFMA-of-ones, scale cancels in o/l. [validated R9]
__global__ __launch_bounds__(256, 4) void attn_mfma(
    const ushort* __restrict__ qB, const ushort* __restrict__ kB,
    const ushort* __restrict__ vT, ushort* __restrict__ aH,
    ushort* __restrict__ aL) {
  __shared__ ushort pB[4][4][512];
  int t = threadIdx.x;
  int lane = t & 63, w = t >> 6;
  int l31 = lane & 31, half = lane >> 5;
  int bh = blockIdx.x;
  int b = bh >> 3, h = bh & 7;
  int q0 = blockIdx.y * 128;

  const ushort* qrow = qB + ((size_t)bh * NN + q0 + w * 32 + l31) * 32;
  short8 bq0 = *(const short8*)(qrow + half * 8);
  short8 bq1 = *(const short8*)(qrow + 16 + half * 8);

  // Per-lane fragment base pointers (direct-from-global MFMA operands):
  //  K A-frag:  K[m0 + tt*32 + l31][half*8 + j (+16 for second x16 slab)]
  //  V^T A-frag: V^T[l31][m0 + kb*16 + half*8 + j]
  const ushort* kfp = kB + (size_t)bh * MM * 32 + (size_t)l31 * 32 + half * 8;
  const ushort* vfp = vT + (size_t)bh * 32 * MM + (size_t)l31 * MM + half * 8;

  short8 ones;
#pragma unroll
  for (int j = 0; j < 8; ++j) ones[j] = (short)0x3F80;   // bf16 1.0

  f32x16 o, lacc;
#pragma unroll
  for (int i = 0; i < 16; ++i) { o[i] = 0.f; lacc[i] = 0.f; }

  for (int mc = 0; mc < 16; ++mc) {
    int m0 = mc * 64;

    // K fragments for this 64-m chunk (2 tiles x 2 k-slabs)
    short8 ak[2][2];
#pragma unroll
    for (int tt = 0; tt < 2; ++tt) {
      const ushort* kp = kfp + (size_t)(m0 + tt * 32) * 32;
      ak[tt][0] = *(const short8*)(kp);
      ak[tt][1] = *(const short8*)(kp + 16);
    }

    // S^T = K·Q^T : two 32x32 tiles
    f32x16 st[2];
#pragma unroll
    for (int tt = 0; tt < 2; ++tt) {
      f32x16 z;
#pragma unroll
      for (int i = 0; i < 16; ++i) z[i] = 0.f;
      z = __builtin_amdgcn_mfma_f32_32x32x16_bf16(ak[tt][0], bq0, z, 0, 0, 0);
      z = __builtin_amdgcn_mfma_f32_32x32x16_bf16(ak[tt][1], bq1, z, 0, 0, 0);
      st[tt] = z;
    }

    // V fragments (needed only after exp2 -> latency hidden under VALU)
    short8 avv[4];
#pragma unroll
    for (int kb = 0; kb < 4; ++kb)
      avv[kb] = *(const short8*)(vfp + m0 + kb * 16);

    // P = exp2(st) (no max subtraction), bf16-truncated, frag-major store
#pragma unroll
    for (int tt = 0; tt < 2; ++tt) {
#pragma unroll
      for (int rg = 0; rg < 4; ++rg) {
        float p0 = EXP2F(st[tt][rg * 4 + 0]);
        float p1 = EXP2F(st[tt][rg * 4 + 1]);
        float p2 = EXP2F(st[tt][rg * 4 + 2]);
        float p3 = EXP2F(st[tt][rg * 4 + 3]);
        uint2 pk;
        pk.x = __builtin_amdgcn_perm(__builtin_bit_cast(unsigned, p1),
                                     __builtin_bit_cast(unsigned, p0), 0x07060302);
        pk.y = __builtin_amdgcn_perm(__builtin_bit_cast(unsigned, p3),
                                     __builtin_bit_cast(unsigned, p2), 0x07060302);
        *(uint2*)&pB[w][2 * tt + (rg >> 1)][((rg & 1) * 32 + l31) * 8 + 4 * half] = pk;
      }
    }

    // O^T += V^T·P ; lacc += ones·P (denominator from the same stored P)
#pragma unroll
    for (int kb = 0; kb < 4; ++kb) {
      short8 bp = *(const short8*)&pB[w][kb][lane * 8];
      o = __builtin_amdgcn_mfma_f32_32x32x16_bf16(avv[kb], bp, o, 0, 0, 0);
      lacc = __builtin_amdgcn_mfma_f32_32x32x16_bf16(ones, bp, lacc, 0, 0, 0);
    }
  }

  float inv = 1.f / lacc[0];
  size_t rbase = ((size_t)b * NN + q0 + w * 32 + l31) * 256 + h * 32;
#pragma unroll
  for (int rg = 0; rg < 4; ++rg) {
#pragma unroll
    for (int j = 0; j < 4; ++j) {
      float v = o[rg * 4 + j] * inv;
      ushort hi = f2bf(v);
      ushort lo = f2bf(v - bf2f(hi));
      int d = rg * 8 + half * 4 + j;
      aH[rbase + d] = hi;
      aL[rbase + d] = lo;
    }
  }
}

// ---------------------------------------------------------------------------
// 4) proj GEMM, hi/lo split on A and W, 64x64 tiles.
//    Now double-buffered single-barrier (mirrors gemm_qkv pattern; was
//    single-buffer with 2 barriers/iter). LDS 40 KB -> 4 blocks/CU, grid
//    1024 = exactly resident.
__global__ __launch_bounds__(256) void gemm_proj(
    const ushort* __restrict__ A, const ushort* __restrict__ A2,
    const float* __restrict__ W, const float* __restrict__ bias,
    float* __restrict__ out) {
  __shared__ ushort smem[2][4 * 64 * 40];
  constexpr int OA = 0, OA2 = 64 * 40, OW = 2 * 64 * 40, OW2 = 3 * 64 * 40;
  int bid = blockIdx.x;
  int r0 = (bid >> 2) * 64, c0 = (bid & 3) * 64;

  int t = threadIdx.x;
  int lane = t & 63, w = t >> 6;
  int l31 = lane & 31, half = lane >> 5;
  int wr = w >> 1, wc = w & 1;
  int rowA = t >> 2, kq = (t & 3) * 8;

  f32x16 acc;
#pragma unroll
  for (int i = 0; i < 16; ++i) acc[i] = 0.f;

  short8 ra, ra2;
  float4 rw0, rw1;
  auto prefetch = [&](int kc) {
    ra = *(const short8*)&A[(size_t)(r0 + rowA) * 256 + kc + kq];
    ra2 = *(const short8*)&A2[(size_t)(r0 + rowA) * 256 + kc + kq];
    const float* wp = &W[(size_t)(c0 + rowA) * 256 + kc + kq];
    rw0 = *(const float4*)wp;
    rw1 = *(const float4*)(wp + 4);
  };
  auto store = [&](ushort* buf) {
    *(short8*)&buf[OA + rowA * 40 + kq] = ra;
    *(short8*)&buf[OA2 + rowA * 40 + kq] = ra2;
    float vals[8] = {rw0.x, rw0.y, rw0.z, rw0.w, rw1.x, rw1.y, rw1.z, rw1.w};
    short8 hi, lo;
#pragma unroll
    for (int j = 0; j < 8; ++j) {
      hi[j] = (short)f2bf(vals[j]);
      lo[j] = (short)f2bf(vals[j] - bf2f((ushort)hi[j]));
    }
    *(short8*)&buf[OW + rowA * 40 + kq] = hi;
    *(short8*)&buf[OW2 + rowA * 40 + kq] = lo;
  };

  prefetch(0);
  store(smem[0]);
  __syncthreads();
  for (int i = 0; i < 8; ++i) {
    ushort* cur = smem[i & 1];
    ushort* nxt = smem[(i & 1) ^ 1];
    if (i < 7) prefetch((i + 1) * 32);
#pragma unroll
    for (int ks = 0; ks < 2; ++ks) {
      int ro = (wr * 32 + l31) * 40 + ks * 16 + half * 8;
      int co = (wc * 32 + l31) * 40 + ks * 16 + half * 8;
      short8 af = *(const short8*)&cur[OA + ro];
      short8 af2 = *(const short8*)&cur[OA2 + ro];
      short8 wf = *(const short8*)&cur[OW + co];
      short8 wf2 = *(const short8*)&cur[OW2 + co];
      acc = __builtin_amdgcn_mfma_f32_32x32x16_bf16(af, wf, acc, 0, 0, 0);
      acc = __builtin_amdgcn_mfma_f32_32x32x16_bf16(af2, wf, acc, 0, 0, 0);
      acc = __builtin_amdgcn_mfma_f32_32x32x16_bf16(af, wf2, acc, 0, 0, 0);
    }
    if (i < 7) store(nxt);
    __syncthreads();
  }

#pragma unroll
  for (int i = 0; i < 16; ++i) {
    int rl = (i & 3) + 8 * (i >> 2) + 4 * half;
    int r = r0 + wr * 32 + rl;
    int c = c0 + wc * 32 + l31;
    out[(size_t)r * 256 + c] = acc[i] + bias[c];
  }
}

// ---------------------------------------------------------------------------
extern "C" void kernel_launch(void* const* d_in, const int* in_sizes, int n_in,
                              void* d_out, int out_size, void* d_ws, size_t ws_size,
                              hipStream_t stream) {
  const float* x      = (const float*)d_in[0];
  const float* dw_w   = (const float*)d_in[1];
  const float* dw_b   = (const float*)d_in[2];
  const float* pw_w   = (const float*)d_in[3];
  const float* pw_b   = (const float*)d_in[4];
  const float* sr_w   = (const float*)d_in[5];
  const float* ln_g   = (const float*)d_in[6];
  const float* ln_b   = (const float*)d_in[7];
  const float* kv_w   = (const float*)d_in[8];
  const float* kv_b   = (const float*)d_in[9];
  const float* proj_w = (const float*)d_in[10];
  const float* proj_b = (const float*)d_in[11];
  float* out = (float*)d_out;

  char* ws = (char*)d_ws;
  ushort* q1b = (ushort*)(ws);                  // 16384x256 bf16  (8 MB)
  ushort* xsr = (ushort*)(ws + (8u << 20));     // 4096x256        (2 MB)
  ushort* qB  = (ushort*)(ws + (16u << 20));    // 32x4096x32      (8 MB)
  ushort* kBp = (ushort*)(ws + (24u << 20));    // 32x1024x32      (2 MB)
  ushort* vTp = (ushort*)(ws + (26u << 20));    // 32x32x1024      (2 MB)
  ushort* aH  = (ushort*)(ws + (28u << 20));    // 16384x256       (8 MB)
  ushort* aL  = (ushort*)(ws + (36u << 20));    // 16384x256       (8 MB)

  pre_fused<<<dim3(4608), 256, 0, stream>>>(x, dw_w, dw_b, sr_w, ln_g, ln_b,
                                            q1b, xsr);
  gemm_qkv<<<dim3(1536), 256, 0, stream>>>(q1b, xsr, pw_w, pw_b, kv_w, kv_b,
                                           qB, kBp, vTp);
  attn_mfma<<<dim3(32, 32), 256, 0, stream>>>(qB, kBp, vTp, aH, aL);
  gemm_proj<<<dim3(1024), 256, 0, stream>>>(aH, aL, proj_w, proj_b, out);
}

// Round 2
// 169.029 us; speedup vs baseline: 1.1082x; 1.1082x over previous
//
#include <hip/hip_runtime.h>
#include <math.h>

#define BB 4
#define HH 64
#define WW 64
#define CC 256
#define NN 4096   // H*W
#define MM 1024   // (H/2)*(W/2)
#define LN_EPS 1e-6f
#define SLF (0.17677669529663687f * 1.4426950408889634f)

typedef __attribute__((ext_vector_type(8)))  short short8;
typedef __attribute__((ext_vector_type(16))) float f32x16;

__device__ __forceinline__ ushort f2bf(float f) {
  unsigned u = __builtin_bit_cast(unsigned, f);
  u += 0x7fffu + ((u >> 16) & 1u);   // RNE
  return (ushort)(u >> 16);
}
__device__ __forceinline__ float bf2f(ushort h) {
  unsigned u = ((unsigned)h) << 16;
  return __builtin_bit_cast(float, u);
}
#if __has_builtin(__builtin_amdgcn_exp2f)
#define EXP2F(x) __builtin_amdgcn_exp2f(x)
#else
#define EXP2F(x) exp2f(x)
#endif

// ---------------------------------------------------------------------------
// 1) FUSED front end: blocks [0,4096): srln; blocks [4096,4608): dwconv
__global__ __launch_bounds__(256) void pre_fused(
    const float* __restrict__ x, const float* __restrict__ dw_w,
    const float* __restrict__ dw_b, const float* __restrict__ sr_w,
    const float* __restrict__ ln_g, const float* __restrict__ ln_b,
    ushort* __restrict__ q1b, ushort* __restrict__ xsr) {
  int bid = blockIdx.x;
  int c = threadIdx.x;
  if (bid < 4096) {
    int b = bid >> 10, m = bid & 1023;
    int my = m >> 5, mx = m & 31;
    const float* xb = x + (size_t)b * NN * CC + c;
    float acc = 0.f;
#pragma unroll
    for (int dy = 0; dy < 3; ++dy) {
      int iy = 2 * my + dy - 1;
      if (iy < 0 || iy >= HH) continue;
#pragma unroll
      for (int dx = 0; dx < 3; ++dx) {
        int ix = 2 * mx + dx - 1;
        if (ix < 0 || ix >= WW) continue;
        acc += xb[(size_t)(iy * WW + ix) * CC] * sr_w[c * 9 + dy * 3 + dx];
      }
    }
    float v1 = acc, v2 = acc * acc;
#pragma unroll
    for (int s = 1; s < 64; s <<= 1) {
      v1 += __shfl_xor(v1, s);
      v2 += __shfl_xor(v2, s);
    }
    __shared__ float r1[4], r2[4];
    int lane = c & 63, wv = c >> 6;
    if (lane == 0) { r1[wv] = v1; r2[wv] = v2; }
    __syncthreads();
    float s1 = r1[0] + r1[1] + r1[2] + r1[3];
    float s2 = r2[0] + r2[1] + r2[2] + r2[3];
    float mu = s1 * (1.f / 256.f);
    float var = s2 * (1.f / 256.f) - mu * mu;
    float yv = (acc - mu) * rsqrtf(var + LN_EPS) * ln_g[c] + ln_b[c];
    xsr[((size_t)b * MM + m) * CC + c] = f2bf(yv);
  } else {
    int id = bid - 4096;
    int b = id >> 7, yy = id & 127;
    int y = yy >> 1, hf = yy & 1;
    float wr[9];
#pragma unroll
    for (int i = 0; i < 9; ++i) wr[i] = dw_w[c * 9 + i];
    float bi = dw_b[c];
    const float* xb = x + (size_t)b * NN * CC + c;
    int x0 = hf * 32;
    bool okT = (y > 0), okB = (y < 63);
    float a0, a1, a2, b0, b1, b2;
    if (x0 == 0) {
      a0 = a1 = a2 = 0.f;
    } else {
      a0 = okT ? xb[(size_t)((y - 1) * 64 + x0 - 1) * CC] : 0.f;
      a1 = xb[(size_t)(y * 64 + x0 - 1) * CC];
      a2 = okB ? xb[(size_t)((y + 1) * 64 + x0 - 1) * CC] : 0.f;
    }
    b0 = okT ? xb[(size_t)((y - 1) * 64 + x0) * CC] : 0.f;
    b1 = xb[(size_t)(y * 64 + x0) * CC];
    b2 = okB ? xb[(size_t)((y + 1) * 64 + x0) * CC] : 0.f;
    ushort* ob = q1b + ((size_t)b * NN + y * 64) * CC + c;
#pragma unroll 8
    for (int xx = x0; xx < x0 + 32; ++xx) {
      float c0v, c1v, c2v;
      if (xx < 63) {
        c0v = okT ? xb[(size_t)((y - 1) * 64 + xx + 1) * CC] : 0.f;
        c1v = xb[(size_t)(y * 64 + xx + 1) * CC];
        c2v = okB ? xb[(size_t)((y + 1) * 64 + xx + 1) * CC] : 0.f;
      } else {
        c0v = c1v = c2v = 0.f;
      }
      float acc = bi;
      acc += a0 * wr[0] + b0 * wr[1] + c0v * wr[2];
      acc += a1 * wr[3] + b1 * wr[4] + c1v * wr[5];
      acc += a2 * wr[6] + b2 * wr[7] + c2v * wr[8];
      ob[(size_t)xx * CC] = f2bf(acc);
      a0 = b0; a1 = b1; a2 = b2;
      b0 = c0v; b1 = c1v; b2 = c2v;
    }
  }
}

// ---------------------------------------------------------------------------
// 2) FUSED q-GEMM + kv-GEMM. 64x64 tiles, double-buffered single-barrier.
__global__ __launch_bounds__(256) void gemm_qkv(
    const ushort* __restrict__ q1b, const ushort* __restrict__ xsr,
    const float* __restrict__ pw_w, const float* __restrict__ pw_b,
    const float* __restrict__ kv_w, const float* __restrict__ kv_b,
    ushort* __restrict__ qB, ushort* __restrict__ kB,
    ushort* __restrict__ vT) {
  __shared__ ushort smem[2][128 * 40];
  int bid = blockIdx.x;
  bool is0 = bid < 1024;
  const ushort* A;
  const float* W;
  const float* bias;
  int r0, c0;
  if (is0) {
    A = q1b; W = pw_w; bias = pw_b;
    r0 = (bid >> 2) * 64; c0 = (bid & 3) * 64;
  } else {
    int sid = bid - 1024;
    A = xsr; W = kv_w; bias = kv_b;
    r0 = (sid >> 3) * 64; c0 = (sid & 7) * 64;
  }
  const bool vmode = (!is0) && (c0 >= 256);

  int t = threadIdx.x;
  int lane = t & 63, w = t >> 6;
  int l31 = lane & 31, half = lane >> 5;
  int wr = w >> 1, wc = w & 1;
  int rowA = t >> 2, kq = (t & 3) * 8;

  f32x16 acc;
#pragma unroll
  for (int i = 0; i < 16; ++i) acc[i] = 0.f;

  short8 ra;
  float4 rw0, rw1;
  auto prefetch = [&](int kc) {
    ra = *(const short8*)&A[(size_t)(r0 + rowA) * 256 + kc + kq];
    const float* wp = &W[(size_t)(c0 + rowA) * 256 + kc + kq];
    rw0 = *(const float4*)wp;
    rw1 = *(const float4*)(wp + 4);
  };
  auto store = [&](ushort* buf) {
    *(short8*)&buf[rowA * 40 + kq] = ra;
    float vals[8] = {rw0.x, rw0.y, rw0.z, rw0.w, rw1.x, rw1.y, rw1.z, rw1.w};
    short8 hi;
#pragma unroll
    for (int j = 0; j < 8; ++j) hi[j] = (short)f2bf(vals[j]);
    *(short8*)&buf[64 * 40 + rowA * 40 + kq] = hi;
  };

  prefetch(0);
  store(smem[0]);
  __syncthreads();
  for (int i = 0; i < 8; ++i) {
    ushort* cur = smem[i & 1];
    ushort* nxt = smem[(i & 1) ^ 1];
    if (i < 7) prefetch((i + 1) * 32);
#pragma unroll
    for (int ks = 0; ks < 2; ++ks) {
      short8 af = *(const short8*)&cur[(wr * 32 + l31) * 40 + ks * 16 + half * 8];
      short8 wf = *(const short8*)&cur[64 * 40 + (wc * 32 + l31) * 40 + ks * 16 + half * 8];
      if (vmode)
        acc = __builtin_amdgcn_mfma_f32_32x32x16_bf16(wf, af, acc, 0, 0, 0);
      else
        acc = __builtin_amdgcn_mfma_f32_32x32x16_bf16(af, wf, acc, 0, 0, 0);
    }
    if (i < 7) store(nxt);
    __syncthreads();
  }

#pragma unroll
  for (int i = 0; i < 16; ++i) {
    int rl = (i & 3) + 8 * (i >> 2) + 4 * half;
    if (is0) {
      int r = r0 + wr * 32 + rl;
      int c = c0 + wc * 32 + l31;
      int b = r >> 12, n = r & 4095;
      int h = c >> 5, d = c & 31;
      qB[((size_t)(b * 8 + h) * NN + n) * 32 + d] =
          f2bf((acc[i] + bias[c]) * SLF);
    } else if (!vmode) {
      int r = r0 + wr * 32 + rl;
      int c = c0 + wc * 32 + l31;
      int b = r >> 10, m = r & 1023;
      int h = c >> 5, d = c & 31;
      kB[((size_t)(b * 8 + h) * MM + m) * 32 + d] = f2bf(acc[i] + bias[c]);
    } else {
      int c = c0 + wc * 32 + rl;
      int r = r0 + wr * 32 + l31;
      int b = r >> 10, m = r & 1023;
      int cv = c - 256;
      int h = cv >> 5, d = cv & 31;
      vT[((size_t)(b * 8 + h) * 32 + d) * MM + m] = f2bf(acc[i] + bias[c]);
    }
  }
}

// ---------------------------------------------------------------------------
// 3) MFMA flash attention — staged K/V restored (round-1's direct-global V
//    fragment loads were a transaction storm: 64 lanes x 2KB stride = 64
//    cache lines per instruction, no sharing across warps -> latency-bound,
//    MfmaUtil 17%). Cooperative staged loads are 8 lines/inst and shared by
//    all 4 warps. New vs the validated R9 version:
//      (a) next-chunk LDS stores moved EARLY (right after QK^T) so the
//          end-of-iter barrier's lgkm/vm drain is shadowed by exp2+PV (T14);
//      (b) s_setprio(1) around both MFMA clusters (T5; blocks on a CU are
//          staggered, so priority arbitration has role diversity).
//    Math unchanged: no online max (scores bounded in log2 domain), P =
//    exp2(st), denominator via MFMA-of-ones, scale cancels in o/l.
__global__ __launch_bounds__(256, 4) void attn_mfma(
    const ushort* __restrict__ qB, const ushort* __restrict__ kB,
    const ushort* __restrict__ vT, ushort* __restrict__ aH,
    ushort* __restrict__ aL) {
  __shared__ ushort sKa[2][8][264];
  __shared__ ushort sVa[2][8][264];
  __shared__ ushort pB[4][4][512];
  int t = threadIdx.x;
  int lane = t & 63, w = t >> 6;
  int l31 = lane & 31, half = lane >> 5;
  int bh = blockIdx.x;
  int b = bh >> 3, h = bh & 7;
  int q0 = blockIdx.y * 128;

  const ushort* qrow = qB + ((size_t)bh * NN + q0 + w * 32 + l31) * 32;
  short8 bq0 = *(const short8*)(qrow + half * 8);
  short8 bq1 = *(const short8*)(qrow + 16 + half * 8);

  const ushort* kbase = kB + (size_t)bh * MM * 32;
  const ushort* vbase = vT + (size_t)bh * 32 * MM;
  int krow = t >> 2, kq = (t & 3) * 8;
  int vd = t >> 3, vmo = (t & 7) * 8;
  int kreg_idx = (krow >> 5) * 4 + (kq >> 4) * 2 + ((kq >> 3) & 1);
  int klane = (krow & 31) * 8;
  int vreg_idx = (vmo >> 4) * 2 + ((vmo >> 3) & 1);
  int vlane = vd * 8;

  short8 ones;
#pragma unroll
  for (int j = 0; j < 8; ++j) ones[j] = (short)0x3F80;   // bf16 1.0

  short8 kreg = *(const short8*)&kbase[(size_t)krow * 32 + kq];
  short8 vreg = *(const short8*)&vbase[(size_t)vd * MM + vmo];
  *(short8*)&sKa[0][kreg_idx][klane] = kreg;
  *(short8*)&sVa[0][vreg_idx][vlane] = vreg;

  f32x16 o, lacc;
#pragma unroll
  for (int i = 0; i < 16; ++i) { o[i] = 0.f; lacc[i] = 0.f; }
  __syncthreads();

  for (int mc = 0; mc < 16; ++mc) {
    int cur = mc & 1, nxt = cur ^ 1;
    if (mc < 15) {
      int m0n = (mc + 1) * 64;
      kreg = *(const short8*)&kbase[(size_t)(m0n + krow) * 32 + kq];
      vreg = *(const short8*)&vbase[(size_t)vd * MM + m0n + vmo];
    }
    // S^T = K·Q^T : two 32x32 tiles
    f32x16 st[2];
    __builtin_amdgcn_s_setprio(1);
#pragma unroll
    for (int tt = 0; tt < 2; ++tt) {
      short8 a0 = *(const short8*)&sKa[cur][tt * 4 + 0 + half][l31 * 8];
      short8 a1 = *(const short8*)&sKa[cur][tt * 4 + 2 + half][l31 * 8];
      f32x16 z;
#pragma unroll
      for (int i = 0; i < 16; ++i) z[i] = 0.f;
      z = __builtin_amdgcn_mfma_f32_32x32x16_bf16(a0, bq0, z, 0, 0, 0);
      z = __builtin_amdgcn_mfma_f32_32x32x16_bf16(a1, bq1, z, 0, 0, 0);
      st[tt] = z;
    }
    __builtin_amdgcn_s_setprio(0);

    // EARLY store of the next chunk (different buffer than 'cur' -> no
    // alias with any warp's reads this iteration). exp2+PV below shadow
    // the LDS-write latency, so the end barrier's drain is ~free.
    if (mc < 15) {
      *(short8*)&sKa[nxt][kreg_idx][klane] = kreg;
      *(short8*)&sVa[nxt][vreg_idx][vlane] = vreg;
    }

    // P = exp2(st) (no max subtraction), bf16-truncated, frag-major store
#pragma unroll
    for (int tt = 0; tt < 2; ++tt) {
#pragma unroll
      for (int rg = 0; rg < 4; ++rg) {
        float p0 = EXP2F(st[tt][rg * 4 + 0]);
        float p1 = EXP2F(st[tt][rg * 4 + 1]);
        float p2 = EXP2F(st[tt][rg * 4 + 2]);
        float p3 = EXP2F(st[tt][rg * 4 + 3]);
        uint2 pk;
        pk.x = __builtin_amdgcn_perm(__builtin_bit_cast(unsigned, p1),
                                     __builtin_bit_cast(unsigned, p0), 0x07060302);
        pk.y = __builtin_amdgcn_perm(__builtin_bit_cast(unsigned, p3),
                                     __builtin_bit_cast(unsigned, p2), 0x07060302);
        *(uint2*)&pB[w][2 * tt + (rg >> 1)][((rg & 1) * 32 + l31) * 8 + 4 * half] = pk;
      }
    }

    // O^T += V^T·P ; lacc += ones·P (denominator from the same stored P)
    __builtin_amdgcn_s_setprio(1);
#pragma unroll
    for (int kb = 0; kb < 4; ++kb) {
      short8 av = *(const short8*)&sVa[cur][kb * 2 + half][l31 * 8];
      short8 bp = *(const short8*)&pB[w][kb][lane * 8];
      o = __builtin_amdgcn_mfma_f32_32x32x16_bf16(av, bp, o, 0, 0, 0);
      lacc = __builtin_amdgcn_mfma_f32_32x32x16_bf16(ones, bp, lacc, 0, 0, 0);
    }
    __builtin_amdgcn_s_setprio(0);

    __syncthreads();
  }

  float inv = 1.f / lacc[0];
  size_t rbase = ((size_t)b * NN + q0 + w * 32 + l31) * 256 + h * 32;
#pragma unroll
  for (int rg = 0; rg < 4; ++rg) {
#pragma unroll
    for (int j = 0; j < 4; ++j) {
      float v = o[rg * 4 + j] * inv;
      ushort hi = f2bf(v);
      ushort lo = f2bf(v - bf2f(hi));
      int d = rg * 8 + half * 4 + j;
      aH[rbase + d] = hi;
      aL[rbase + d] = lo;
    }
  }
}

// ---------------------------------------------------------------------------
// 4) proj GEMM, hi/lo split on A and W, 64x64 tiles, double-buffered
//    single-barrier (mirrors gemm_qkv pattern).
__global__ __launch_bounds__(256) void gemm_proj(
    const ushort* __restrict__ A, const ushort* __restrict__ A2,
    const float* __restrict__ W, const float* __restrict__ bias,
    float* __restrict__ out) {
  __shared__ ushort smem[2][4 * 64 * 40];
  constexpr int OA = 0, OA2 = 64 * 40, OW = 2 * 64 * 40, OW2 = 3 * 64 * 40;
  int bid = blockIdx.x;
  int r0 = (bid >> 2) * 64, c0 = (bid & 3) * 64;

  int t = threadIdx.x;
  int lane = t & 63, w = t >> 6;
  int l31 = lane & 31, half = lane >> 5;
  int wr = w >> 1, wc = w & 1;
  int rowA = t >> 2, kq = (t & 3) * 8;

  f32x16 acc;
#pragma unroll
  for (int i = 0; i < 16; ++i) acc[i] = 0.f;

  short8 ra, ra2;
  float4 rw0, rw1;
  auto prefetch = [&](int kc) {
    ra = *(const short8*)&A[(size_t)(r0 + rowA) * 256 + kc + kq];
    ra2 = *(const short8*)&A2[(size_t)(r0 + rowA) * 256 + kc + kq];
    const float* wp = &W[(size_t)(c0 + rowA) * 256 + kc + kq];
    rw0 = *(const float4*)wp;
    rw1 = *(const float4*)(wp + 4);
  };
  auto store = [&](ushort* buf) {
    *(short8*)&buf[OA + rowA * 40 + kq] = ra;
    *(short8*)&buf[OA2 + rowA * 40 + kq] = ra2;
    float vals[8] = {rw0.x, rw0.y, rw0.z, rw0.w, rw1.x, rw1.y, rw1.z, rw1.w};
    short8 hi, lo;
#pragma unroll
    for (int j = 0; j < 8; ++j) {
      hi[j] = (short)f2bf(vals[j]);
      lo[j] = (short)f2bf(vals[j] - bf2f((ushort)hi[j]));
    }
    *(short8*)&buf[OW + rowA * 40 + kq] = hi;
    *(short8*)&buf[OW2 + rowA * 40 + kq] = lo;
  };

  prefetch(0);
  store(smem[0]);
  __syncthreads();
  for (int i = 0; i < 8; ++i) {
    ushort* cur = smem[i & 1];
    ushort* nxt = smem[(i & 1) ^ 1];
    if (i < 7) prefetch((i + 1) * 32);
#pragma unroll
    for (int ks = 0; ks < 2; ++ks) {
      int ro = (wr * 32 + l31) * 40 + ks * 16 + half * 8;
      int co = (wc * 32 + l31) * 40 + ks * 16 + half * 8;
      short8 af = *(const short8*)&cur[OA + ro];
      short8 af2 = *(const short8*)&cur[OA2 + ro];
      short8 wf = *(const short8*)&cur[OW + co];
      short8 wf2 = *(const short8*)&cur[OW2 + co];
      acc = __builtin_amdgcn_mfma_f32_32x32x16_bf16(af, wf, acc, 0, 0, 0);
      acc = __builtin_amdgcn_mfma_f32_32x32x16_bf16(af2, wf, acc, 0, 0, 0);
      acc = __builtin_amdgcn_mfma_f32_32x32x16_bf16(af, wf2, acc, 0, 0, 0);
    }
    if (i < 7) store(nxt);
    __syncthreads();
  }

#pragma unroll
  for (int i = 0; i < 16; ++i) {
    int rl = (i & 3) + 8 * (i >> 2) + 4 * half;
    int r = r0 + wr * 32 + rl;
    int c = c0 + wc * 32 + l31;
    out[(size_t)r * 256 + c] = acc[i] + bias[c];
  }
}

// ---------------------------------------------------------------------------
extern "C" void kernel_launch(void* const* d_in, const int* in_sizes, int n_in,
                              void* d_out, int out_size, void* d_ws, size_t ws_size,
                              hipStream_t stream) {
  const float* x      = (const float*)d_in[0];
  const float* dw_w   = (const float*)d_in[1];
  const float* dw_b   = (const float*)d_in[2];
  const float* pw_w   = (const float*)d_in[3];
  const float* pw_b   = (const float*)d_in[4];
  const float* sr_w   = (const float*)d_in[5];
  const float* ln_g   = (const float*)d_in[6];
  const float* ln_b   = (const float*)d_in[7];
  const float* kv_w   = (const float*)d_in[8];
  const float* kv_b   = (const float*)d_in[9];
  const float* proj_w = (const float*)d_in[10];
  const float* proj_b = (const float*)d_in[11];
  float* out = (float*)d_out;

  char* ws = (char*)d_ws;
  ushort* q1b = (ushort*)(ws);                  // 16384x256 bf16  (8 MB)
  ushort* xsr = (ushort*)(ws + (8u << 20));     // 4096x256        (2 MB)
  ushort* qB  = (ushort*)(ws + (16u << 20));    // 32x4096x32      (8 MB)
  ushort* kBp = (ushort*)(ws + (24u << 20));    // 32x1024x32      (2 MB)
  ushort* vTp = (ushort*)(ws + (26u << 20));    // 32x32x1024      (2 MB)
  ushort* aH  = (ushort*)(ws + (28u << 20));    // 16384x256       (8 MB)
  ushort* aL  = (ushort*)(ws + (36u << 20));    // 16384x256       (8 MB)

  pre_fused<<<dim3(4608), 256, 0, stream>>>(x, dw_w, dw_b, sr_w, ln_g, ln_b,
                                            q1b, xsr);
  gemm_qkv<<<dim3(1536), 256, 0, stream>>>(q1b, xsr, pw_w, pw_b, kv_w, kv_b,
                                           qB, kBp, vTp);
  attn_mfma<<<dim3(32, 32), 256, 0, stream>>>(qB, kBp, vTp, aH, aL);
  gemm_proj<<<dim3(1024), 256, 0, stream>>>(aH, aL, proj_w, proj_b, out);
}

// Round 4
// 164.282 us; speedup vs baseline: 1.1402x; 1.0289x over previous
//
#include <hip/hip_runtime.h>
#include <math.h>

#define BB 4
#define HH 64
#define WW 64
#define CC 256
#define NN 4096   // H*W
#define MM 1024   // (H/2)*(W/2)
#define LN_EPS 1e-6f
#define SLF (0.17677669529663687f * 1.4426950408889634f)

typedef __attribute__((ext_vector_type(8)))  short short8;
typedef __attribute__((ext_vector_type(16))) float f32x16;

__device__ __forceinline__ ushort f2bf(float f) {
  unsigned u = __builtin_bit_cast(unsigned, f);
  u += 0x7fffu + ((u >> 16) & 1u);   // RNE
  return (ushort)(u >> 16);
}
__device__ __forceinline__ float bf2f(ushort h) {
  unsigned u = ((unsigned)h) << 16;
  return __builtin_bit_cast(float, u);
}
#if __has_builtin(__builtin_amdgcn_exp2f)
#define EXP2F(x) __builtin_amdgcn_exp2f(x)
#else
#define EXP2F(x) exp2f(x)
#endif

// ---------------------------------------------------------------------------
// 1) FUSED front end.
//    blocks [0,4096):      srln (strided dwconv + LayerNorm -> xsr bf16)
//    blocks [4096,4608):   dwconv 3x3 (q path stage 1 -> q1b bf16)
//    blocks [4608,4672):   pw_w  f32 -> bf16 (one-time weight convert)
//    blocks [4672,4800):   kv_w  f32 -> bf16
//    blocks [4800,4864):   proj_w f32 -> bf16 hi/lo split
//    The converts remove per-block f32->bf16 work from the GEMM staging
//    paths (was redone by up to 256 blocks each) and halve W global bytes.
__global__ __launch_bounds__(256) void pre_fused(
    const float* __restrict__ x, const float* __restrict__ dw_w,
    const float* __restrict__ dw_b, const float* __restrict__ sr_w,
    const float* __restrict__ ln_g, const float* __restrict__ ln_b,
    const float* __restrict__ pw_w, const float* __restrict__ kv_w,
    const float* __restrict__ proj_w,
    ushort* __restrict__ q1b, ushort* __restrict__ xsr,
    ushort* __restrict__ pwB, ushort* __restrict__ kvB,
    ushort* __restrict__ pjH, ushort* __restrict__ pjL) {
  int bid = blockIdx.x;
  int c = threadIdx.x;
  if (bid < 4096) {
    int b = bid >> 10, m = bid & 1023;
    int my = m >> 5, mx = m & 31;
    const float* xb = x + (size_t)b * NN * CC + c;
    float acc = 0.f;
#pragma unroll
    for (int dy = 0; dy < 3; ++dy) {
      int iy = 2 * my + dy - 1;
      if (iy < 0 || iy >= HH) continue;
#pragma unroll
      for (int dx = 0; dx < 3; ++dx) {
        int ix = 2 * mx + dx - 1;
        if (ix < 0 || ix >= WW) continue;
        acc += xb[(size_t)(iy * WW + ix) * CC] * sr_w[c * 9 + dy * 3 + dx];
      }
    }
    float v1 = acc, v2 = acc * acc;
#pragma unroll
    for (int s = 1; s < 64; s <<= 1) {
      v1 += __shfl_xor(v1, s);
      v2 += __shfl_xor(v2, s);
    }
    __shared__ float r1[4], r2[4];
    int lane = c & 63, wv = c >> 6;
    if (lane == 0) { r1[wv] = v1; r2[wv] = v2; }
    __syncthreads();
    float s1 = r1[0] + r1[1] + r1[2] + r1[3];
    float s2 = r2[0] + r2[1] + r2[2] + r2[3];
    float mu = s1 * (1.f / 256.f);
    float var = s2 * (1.f / 256.f) - mu * mu;
    float yv = (acc - mu) * rsqrtf(var + LN_EPS) * ln_g[c] + ln_b[c];
    xsr[((size_t)b * MM + m) * CC + c] = f2bf(yv);
  } else if (bid < 4608) {
    int id = bid - 4096;
    int b = id >> 7, yy = id & 127;
    int y = yy >> 1, hf = yy & 1;
    float wr[9];
#pragma unroll
    for (int i = 0; i < 9; ++i) wr[i] = dw_w[c * 9 + i];
    float bi = dw_b[c];
    const float* xb = x + (size_t)b * NN * CC + c;
    int x0 = hf * 32;
    bool okT = (y > 0), okB = (y < 63);
    float a0, a1, a2, b0, b1, b2;
    if (x0 == 0) {
      a0 = a1 = a2 = 0.f;
    } else {
      a0 = okT ? xb[(size_t)((y - 1) * 64 + x0 - 1) * CC] : 0.f;
      a1 = xb[(size_t)(y * 64 + x0 - 1) * CC];
      a2 = okB ? xb[(size_t)((y + 1) * 64 + x0 - 1) * CC] : 0.f;
    }
    b0 = okT ? xb[(size_t)((y - 1) * 64 + x0) * CC] : 0.f;
    b1 = xb[(size_t)(y * 64 + x0) * CC];
    b2 = okB ? xb[(size_t)((y + 1) * 64 + x0) * CC] : 0.f;
    ushort* ob = q1b + ((size_t)b * NN + y * 64) * CC + c;
#pragma unroll 8
    for (int xx = x0; xx < x0 + 32; ++xx) {
      float c0v, c1v, c2v;
      if (xx < 63) {
        c0v = okT ? xb[(size_t)((y - 1) * 64 + xx + 1) * CC] : 0.f;
        c1v = xb[(size_t)(y * 64 + xx + 1) * CC];
        c2v = okB ? xb[(size_t)((y + 1) * 64 + xx + 1) * CC] : 0.f;
      } else {
        c0v = c1v = c2v = 0.f;
      }
      float acc = bi;
      acc += a0 * wr[0] + b0 * wr[1] + c0v * wr[2];
      acc += a1 * wr[3] + b1 * wr[4] + c1v * wr[5];
      acc += a2 * wr[6] + b2 * wr[7] + c2v * wr[8];
      ob[(size_t)xx * CC] = f2bf(acc);
      a0 = b0; a1 = b1; a2 = b2;
      b0 = c0v; b1 = c1v; b2 = c2v;
    }
  } else if (bid < 4672) {
    // pw_w: 256x256 f32 -> bf16 (65536 elems = 64 blocks x 1024)
    int i0 = (bid - 4608) * 1024 + c * 4;
    float4 v = *(const float4*)&pw_w[i0];
    ushort tmp[4] = {f2bf(v.x), f2bf(v.y), f2bf(v.z), f2bf(v.w)};
    *(uint2*)&pwB[i0] = *(uint2*)tmp;
  } else if (bid < 4800) {
    // kv_w: 512x256 f32 -> bf16 (131072 elems = 128 blocks x 1024)
    int i0 = (bid - 4672) * 1024 + c * 4;
    float4 v = *(const float4*)&kv_w[i0];
    ushort tmp[4] = {f2bf(v.x), f2bf(v.y), f2bf(v.z), f2bf(v.w)};
    *(uint2*)&kvB[i0] = *(uint2*)tmp;
  } else {
    // proj_w: 256x256 f32 -> bf16 hi/lo (matches gemm_proj's old split)
    int i0 = (bid - 4800) * 1024 + c * 4;
    float4 v = *(const float4*)&proj_w[i0];
    float vv[4] = {v.x, v.y, v.z, v.w};
    ushort th[4], tl[4];
#pragma unroll
    for (int j = 0; j < 4; ++j) {
      th[j] = f2bf(vv[j]);
      tl[j] = f2bf(vv[j] - bf2f(th[j]));
    }
    *(uint2*)&pjH[i0] = *(uint2*)th;
    *(uint2*)&pjL[i0] = *(uint2*)tl;
  }
}

// ---------------------------------------------------------------------------
// 2) FUSED q-GEMM + kv-GEMM. 64x64 tiles, double-buffered single-barrier.
//    W now pre-converted bf16 -> staging is a pure copy (no VALU converts,
//    half the W global bytes).
__global__ __launch_bounds__(256) void gemm_qkv(
    const ushort* __restrict__ q1b, const ushort* __restrict__ xsr,
    const ushort* __restrict__ pwB, const float* __restrict__ pw_b,
    const ushort* __restrict__ kvB, const float* __restrict__ kv_b,
    ushort* __restrict__ qB, ushort* __restrict__ kB,
    ushort* __restrict__ vT) {
  __shared__ ushort smem[2][128 * 40];
  int bid = blockIdx.x;
  bool is0 = bid < 1024;
  const ushort* A;
  const ushort* W;
  const float* bias;
  int r0, c0;
  if (is0) {
    A = q1b; W = pwB; bias = pw_b;
    r0 = (bid >> 2) * 64; c0 = (bid & 3) * 64;
  } else {
    int sid = bid - 1024;
    A = xsr; W = kvB; bias = kv_b;
    r0 = (sid >> 3) * 64; c0 = (sid & 7) * 64;
  }
  const bool vmode = (!is0) && (c0 >= 256);

  int t = threadIdx.x;
  int lane = t & 63, w = t >> 6;
  int l31 = lane & 31, half = lane >> 5;
  int wr = w >> 1, wc = w & 1;
  int rowA = t >> 2, kq = (t & 3) * 8;

  f32x16 acc;
#pragma unroll
  for (int i = 0; i < 16; ++i) acc[i] = 0.f;

  short8 ra, rw;
  auto prefetch = [&](int kc) {
    ra = *(const short8*)&A[(size_t)(r0 + rowA) * 256 + kc + kq];
    rw = *(const short8*)&W[(size_t)(c0 + rowA) * 256 + kc + kq];
  };
  auto store = [&](ushort* buf) {
    *(short8*)&buf[rowA * 40 + kq] = ra;
    *(short8*)&buf[64 * 40 + rowA * 40 + kq] = rw;
  };

  prefetch(0);
  store(smem[0]);
  __syncthreads();
  for (int i = 0; i < 8; ++i) {
    ushort* cur = smem[i & 1];
    ushort* nxt = smem[(i & 1) ^ 1];
    if (i < 7) prefetch((i + 1) * 32);
#pragma unroll
    for (int ks = 0; ks < 2; ++ks) {
      short8 af = *(const short8*)&cur[(wr * 32 + l31) * 40 + ks * 16 + half * 8];
      short8 wf = *(const short8*)&cur[64 * 40 + (wc * 32 + l31) * 40 + ks * 16 + half * 8];
      if (vmode)
        acc = __builtin_amdgcn_mfma_f32_32x32x16_bf16(wf, af, acc, 0, 0, 0);
      else
        acc = __builtin_amdgcn_mfma_f32_32x32x16_bf16(af, wf, acc, 0, 0, 0);
    }
    if (i < 7) store(nxt);
    __syncthreads();
  }

#pragma unroll
  for (int i = 0; i < 16; ++i) {
    int rl = (i & 3) + 8 * (i >> 2) + 4 * half;
    if (is0) {
      int r = r0 + wr * 32 + rl;
      int c = c0 + wc * 32 + l31;
      int b = r >> 12, n = r & 4095;
      int h = c >> 5, d = c & 31;
      qB[((size_t)(b * 8 + h) * NN + n) * 32 + d] =
          f2bf((acc[i] + bias[c]) * SLF);
    } else if (!vmode) {
      int r = r0 + wr * 32 + rl;
      int c = c0 + wc * 32 + l31;
      int b = r >> 10, m = r & 1023;
      int h = c >> 5, d = c & 31;
      kB[((size_t)(b * 8 + h) * MM + m) * 32 + d] = f2bf(acc[i] + bias[c]);
    } else {
      int c = c0 + wc * 32 + rl;
      int r = r0 + wr * 32 + l31;
      int b = r >> 10, m = r & 1023;
      int cv = c - 256;
      int h = cv >> 5, d = cv & 31;
      vT[((size_t)(b * 8 + h) * 32 + d) * MM + m] = f2bf(acc[i] + bias[c]);
    }
  }
}

// ---------------------------------------------------------------------------
// 3) MFMA flash attention, staged K/V, early next-buffer store, setprio.
//    Denominator via in-register f32 add-tree folded into the exp2 loop
//    (+ one shfl_xor(32) at the end) instead of MFMA-of-ones — drops 4 of
//    12 MFMA per chunk and frees 16 AGPRs. Each lane's C/D fragment holds
//    col q=lane&31; lanes l and l+32 hold complementary m-rows, so
//    denom(q) = psum + shfl_xor(psum,32). f32 sum of untruncated P differs
//    from the old bf16 sum by ~4e-6 relative (closer to the f32 reference).
__global__ __launch_bounds__(256, 4) void attn_mfma(
    const ushort* __restrict__ qB, const ushort* __restrict__ kB,
    const ushort* __restrict__ vT, ushort* __restrict__ aH,
    ushort* __restrict__ aL) {
  __shared__ ushort sKa[2][8][264];
  __shared__ ushort sVa[2][8][264];
  __shared__ ushort pB[4][4][512];
  int t = threadIdx.x;
  int lane = t & 63, w = t >> 6;
  int l31 = lane & 31, half = lane >> 5;
  int bh = blockIdx.x;
  int b = bh >> 3, h = bh & 7;
  int q0 = blockIdx.y * 128;

  const ushort* qrow = qB + ((size_t)bh * NN + q0 + w * 32 + l31) * 32;
  short8 bq0 = *(const short8*)(qrow + half * 8);
  short8 bq1 = *(const short8*)(qrow + 16 + half * 8);

  const ushort* kbase = kB + (size_t)bh * MM * 32;
  const ushort* vbase = vT + (size_t)bh * 32 * MM;
  int krow = t >> 2, kq = (t & 3) * 8;
  int vd = t >> 3, vmo = (t & 7) * 8;
  int kreg_idx = (krow >> 5) * 4 + (kq >> 4) * 2 + ((kq >> 3) & 1);
  int klane = (krow & 31) * 8;
  int vreg_idx = (vmo >> 4) * 2 + ((vmo >> 3) & 1);
  int vlane = vd * 8;

  short8 kreg = *(const short8*)&kbase[(size_t)krow * 32 + kq];
  short8 vreg = *(const short8*)&vbase[(size_t)vd * MM + vmo];
  *(short8*)&sKa[0][kreg_idx][klane] = kreg;
  *(short8*)&sVa[0][vreg_idx][vlane] = vreg;

  f32x16 o;
#pragma unroll
  for (int i = 0; i < 16; ++i) o[i] = 0.f;
  float psum = 0.f;
  __syncthreads();

  for (int mc = 0; mc < 16; ++mc) {
    int cur = mc & 1, nxt = cur ^ 1;
    if (mc < 15) {
      int m0n = (mc + 1) * 64;
      kreg = *(const short8*)&kbase[(size_t)(m0n + krow) * 32 + kq];
      vreg = *(const short8*)&vbase[(size_t)vd * MM + m0n + vmo];
    }
    // S^T = K·Q^T : two 32x32 tiles
    f32x16 st[2];
    __builtin_amdgcn_s_setprio(1);
#pragma unroll
    for (int tt = 0; tt < 2; ++tt) {
      short8 a0 = *(const short8*)&sKa[cur][tt * 4 + 0 + half][l31 * 8];
      short8 a1 = *(const short8*)&sKa[cur][tt * 4 + 2 + half][l31 * 8];
      f32x16 z;
#pragma unroll
      for (int i = 0; i < 16; ++i) z[i] = 0.f;
      z = __builtin_amdgcn_mfma_f32_32x32x16_bf16(a0, bq0, z, 0, 0, 0);
      z = __builtin_amdgcn_mfma_f32_32x32x16_bf16(a1, bq1, z, 0, 0, 0);
      st[tt] = z;
    }
    __builtin_amdgcn_s_setprio(0);

    // EARLY store of the next chunk (different buffer than 'cur' -> no
    // alias with any warp's reads this iteration). exp2+PV below shadow
    // the LDS-write latency, so the end barrier's drain is ~free.
    if (mc < 15) {
      *(short8*)&sKa[nxt][kreg_idx][klane] = kreg;
      *(short8*)&sVa[nxt][vreg_idx][vlane] = vreg;
    }

    // P = exp2(st) (no max subtraction), bf16-truncated, frag-major store;
    // f32 row-sum folded in for the softmax denominator.
#pragma unroll
    for (int tt = 0; tt < 2; ++tt) {
#pragma unroll
      for (int rg = 0; rg < 4; ++rg) {
        float p0 = EXP2F(st[tt][rg * 4 + 0]);
        float p1 = EXP2F(st[tt][rg * 4 + 1]);
        float p2 = EXP2F(st[tt][rg * 4 + 2]);
        float p3 = EXP2F(st[tt][rg * 4 + 3]);
        psum += (p0 + p1) + (p2 + p3);
        uint2 pk;
        pk.x = __builtin_amdgcn_perm(__builtin_bit_cast(unsigned, p1),
                                     __builtin_bit_cast(unsigned, p0), 0x07060302);
        pk.y = __builtin_amdgcn_perm(__builtin_bit_cast(unsigned, p3),
                                     __builtin_bit_cast(unsigned, p2), 0x07060302);
        *(uint2*)&pB[w][2 * tt + (rg >> 1)][((rg & 1) * 32 + l31) * 8 + 4 * half] = pk;
      }
    }

    // O^T += V^T·P
    __builtin_amdgcn_s_setprio(1);
#pragma unroll
    for (int kb = 0; kb < 4; ++kb) {
      short8 av = *(const short8*)&sVa[cur][kb * 2 + half][l31 * 8];
      short8 bp = *(const short8*)&pB[w][kb][lane * 8];
      o = __builtin_amdgcn_mfma_f32_32x32x16_bf16(av, bp, o, 0, 0, 0);
    }
    __builtin_amdgcn_s_setprio(0);

    __syncthreads();
  }

  float denom = psum + __shfl_xor(psum, 32);
  float inv = 1.f / denom;
  size_t rbase = ((size_t)b * NN + q0 + w * 32 + l31) * 256 + h * 32;
#pragma unroll
  for (int rg = 0; rg < 4; ++rg) {
#pragma unroll
    for (int j = 0; j < 4; ++j) {
      float v = o[rg * 4 + j] * inv;
      ushort hi = f2bf(v);
      ushort lo = f2bf(v - bf2f(hi));
      int d = rg * 8 + half * 4 + j;
      aH[rbase + d] = hi;
      aL[rbase + d] = lo;
    }
  }
}

// ---------------------------------------------------------------------------
// 4) proj GEMM, hi/lo split on A and W, 64x64 tiles, double-buffered
//    single-barrier. W hi/lo now pre-converted -> staging is a pure copy.
__global__ __launch_bounds__(256) void gemm_proj(
    const ushort* __restrict__ A, const ushort* __restrict__ A2,
    const ushort* __restrict__ Whi, const ushort* __restrict__ Wlo,
    const float* __restrict__ bias, float* __restrict__ out) {
  __shared__ ushort smem[2][4 * 64 * 40];
  constexpr int OA = 0, OA2 = 64 * 40, OW = 2 * 64 * 40, OW2 = 3 * 64 * 40;
  int bid = blockIdx.x;
  int r0 = (bid >> 2) * 64, c0 = (bid & 3) * 64;

  int t = threadIdx.x;
  int lane = t & 63, w = t >> 6;
  int l31 = lane & 31, half = lane >> 5;
  int wr = w >> 1, wc = w & 1;
  int rowA = t >> 2, kq = (t & 3) * 8;

  f32x16 acc;
#pragma unroll
  for (int i = 0; i < 16; ++i) acc[i] = 0.f;

  short8 ra, ra2, rwh, rwl;
  auto prefetch = [&](int kc) {
    ra  = *(const short8*)&A[(size_t)(r0 + rowA) * 256 + kc + kq];
    ra2 = *(const short8*)&A2[(size_t)(r0 + rowA) * 256 + kc + kq];
    rwh = *(const short8*)&Whi[(size_t)(c0 + rowA) * 256 + kc + kq];
    rwl = *(const short8*)&Wlo[(size_t)(c0 + rowA) * 256 + kc + kq];
  };
  auto store = [&](ushort* buf) {
    *(short8*)&buf[OA + rowA * 40 + kq] = ra;
    *(short8*)&buf[OA2 + rowA * 40 + kq] = ra2;
    *(short8*)&buf[OW + rowA * 40 + kq] = rwh;
    *(short8*)&buf[OW2 + rowA * 40 + kq] = rwl;
  };

  prefetch(0);
  store(smem[0]);
  __syncthreads();
  for (int i = 0; i < 8; ++i) {
    ushort* cur = smem[i & 1];
    ushort* nxt = smem[(i & 1) ^ 1];
    if (i < 7) prefetch((i + 1) * 32);
#pragma unroll
    for (int ks = 0; ks < 2; ++ks) {
      int ro = (wr * 32 + l31) * 40 + ks * 16 + half * 8;
      int co = (wc * 32 + l31) * 40 + ks * 16 + half * 8;
      short8 af = *(const short8*)&cur[OA + ro];
      short8 af2 = *(const short8*)&cur[OA2 + ro];
      short8 wf = *(const short8*)&cur[OW + co];
      short8 wf2 = *(const short8*)&cur[OW2 + co];
      acc = __builtin_amdgcn_mfma_f32_32x32x16_bf16(af, wf, acc, 0, 0, 0);
      acc = __builtin_amdgcn_mfma_f32_32x32x16_bf16(af2, wf, acc, 0, 0, 0);
      acc = __builtin_amdgcn_mfma_f32_32x32x16_bf16(af, wf2, acc, 0, 0, 0);
    }
    if (i < 7) store(nxt);
    __syncthreads();
  }

#pragma unroll
  for (int i = 0; i < 16; ++i) {
    int rl = (i & 3) + 8 * (i >> 2) + 4 * half;
    int r = r0 + wr * 32 + rl;
    int c = c0 + wc * 32 + l31;
    out[(size_t)r * 256 + c] = acc[i] + bias[c];
  }
}

// ---------------------------------------------------------------------------
extern "C" void kernel_launch(void* const* d_in, const int* in_sizes, int n_in,
                              void* d_out, int out_size, void* d_ws, size_t ws_size,
                              hipStream_t stream) {
  const float* x      = (const float*)d_in[0];
  const float* dw_w   = (const float*)d_in[1];
  const float* dw_b   = (const float*)d_in[2];
  const float* pw_w   = (const float*)d_in[3];
  const float* pw_b   = (const float*)d_in[4];
  const float* sr_w   = (const float*)d_in[5];
  const float* ln_g   = (const float*)d_in[6];
  const float* ln_b   = (const float*)d_in[7];
  const float* kv_w   = (const float*)d_in[8];
  const float* kv_b   = (const float*)d_in[9];
  const float* proj_w = (const float*)d_in[10];
  const float* proj_b = (const float*)d_in[11];
  float* out = (float*)d_out;

  char* ws = (char*)d_ws;
  ushort* q1b = (ushort*)(ws);                  // 16384x256 bf16  (8 MB)
  ushort* xsr = (ushort*)(ws + (8u << 20));     // 4096x256        (2 MB)
  ushort* qB  = (ushort*)(ws + (16u << 20));    // 32x4096x32      (8 MB)
  ushort* kBp = (ushort*)(ws + (24u << 20));    // 32x1024x32      (2 MB)
  ushort* vTp = (ushort*)(ws + (26u << 20));    // 32x32x1024      (2 MB)
  ushort* aH  = (ushort*)(ws + (28u << 20));    // 16384x256       (8 MB)
  ushort* aL  = (ushort*)(ws + (36u << 20));    // 16384x256       (8 MB)
  ushort* pwB = (ushort*)(ws + (44u << 20));                 // 128 KB
  ushort* kvB = (ushort*)(ws + (44u << 20) + (512u << 10));  // 256 KB
  ushort* pjH = (ushort*)(ws + (45u << 20));                 // 128 KB
  ushort* pjL = (ushort*)(ws + (45u << 20) + (512u << 10));  // 128 KB

  pre_fused<<<dim3(4864), 256, 0, stream>>>(x, dw_w, dw_b, sr_w, ln_g, ln_b,
                                            pw_w, kv_w, proj_w,
                                            q1b, xsr, pwB, kvB, pjH, pjL);
  gemm_qkv<<<dim3(1536), 256, 0, stream>>>(q1b, xsr, pwB, pw_b, kvB, kv_b,
                                           qB, kBp, vTp);
  attn_mfma<<<dim3(32, 32), 256, 0, stream>>>(qB, kBp, vTp, aH, aL);
  gemm_proj<<<dim3(1024), 256, 0, stream>>>(aH, aL, pjH, pjL, proj_b, out);
}

// Round 5
// 155.041 us; speedup vs baseline: 1.2082x; 1.0596x over previous
//
#include <hip/hip_runtime.h>
#include <math.h>

#define BB 4
#define HH 64
#define WW 64
#define CC 256
#define NN 4096   // H*W
#define MM 1024   // (H/2)*(W/2)
#define LN_EPS 1e-6f
#define SLF (0.17677669529663687f * 1.4426950408889634f)

typedef __attribute__((ext_vector_type(8)))  short short8;
typedef __attribute__((ext_vector_type(16))) float f32x16;

__device__ __forceinline__ ushort f2bf(float f) {
  unsigned u = __builtin_bit_cast(unsigned, f);
  u += 0x7fffu + ((u >> 16) & 1u);   // RNE
  return (ushort)(u >> 16);
}
__device__ __forceinline__ float bf2f(ushort h) {
  unsigned u = ((unsigned)h) << 16;
  return __builtin_bit_cast(float, u);
}
#if __has_builtin(__builtin_amdgcn_exp2f)
#define EXP2F(x) __builtin_amdgcn_exp2f(x)
#else
#define EXP2F(x) exp2f(x)
#endif

// ---------------------------------------------------------------------------
// 1) FUSED front end.
//    blocks [0,4096):      srln (strided dwconv + LayerNorm -> xsr bf16)
//    blocks [4096,6144):   dwconv 3x3, 8-col segments (was 32-col; 4x TLP)
//    blocks [6144,6208):   pw_w  f32 -> bf16
//    blocks [6208,6336):   kv_w  f32 -> bf16
//    blocks [6336,6400):   proj_w f32 -> bf16 hi/lo split
__global__ __launch_bounds__(256) void pre_fused(
    const float* __restrict__ x, const float* __restrict__ dw_w,
    const float* __restrict__ dw_b, const float* __restrict__ sr_w,
    const float* __restrict__ ln_g, const float* __restrict__ ln_b,
    const float* __restrict__ pw_w, const float* __restrict__ kv_w,
    const float* __restrict__ proj_w,
    ushort* __restrict__ q1b, ushort* __restrict__ xsr,
    ushort* __restrict__ pwB, ushort* __restrict__ kvB,
    ushort* __restrict__ pjH, ushort* __restrict__ pjL) {
  int bid = blockIdx.x;
  int c = threadIdx.x;
  if (bid < 4096) {
    int b = bid >> 10, m = bid & 1023;
    int my = m >> 5, mx = m & 31;
    const float* xb = x + (size_t)b * NN * CC + c;
    float acc = 0.f;
#pragma unroll
    for (int dy = 0; dy < 3; ++dy) {
      int iy = 2 * my + dy - 1;
      if (iy < 0 || iy >= HH) continue;
#pragma unroll
      for (int dx = 0; dx < 3; ++dx) {
        int ix = 2 * mx + dx - 1;
        if (ix < 0 || ix >= WW) continue;
        acc += xb[(size_t)(iy * WW + ix) * CC] * sr_w[c * 9 + dy * 3 + dx];
      }
    }
    float v1 = acc, v2 = acc * acc;
#pragma unroll
    for (int s = 1; s < 64; s <<= 1) {
      v1 += __shfl_xor(v1, s);
      v2 += __shfl_xor(v2, s);
    }
    __shared__ float r1[4], r2[4];
    int lane = c & 63, wv = c >> 6;
    if (lane == 0) { r1[wv] = v1; r2[wv] = v2; }
    __syncthreads();
    float s1 = r1[0] + r1[1] + r1[2] + r1[3];
    float s2 = r2[0] + r2[1] + r2[2] + r2[3];
    float mu = s1 * (1.f / 256.f);
    float var = s2 * (1.f / 256.f) - mu * mu;
    float yv = (acc - mu) * rsqrtf(var + LN_EPS) * ln_g[c] + ln_b[c];
    xsr[((size_t)b * MM + m) * CC + c] = f2bf(yv);
  } else if (bid < 6144) {
    int id = bid - 4096;                 // 0..2047
    int b = id >> 9, r = id & 511;       // 512 per batch
    int y = r >> 3, seg = r & 7;
    int x0 = seg * 8;
    float wr[9];
#pragma unroll
    for (int i = 0; i < 9; ++i) wr[i] = dw_w[c * 9 + i];
    float bi = dw_b[c];
    const float* xb = x + (size_t)b * NN * CC + c;
    bool okT = (y > 0), okB = (y < 63);
    float a0, a1, a2, b0, b1, b2;
    if (x0 == 0) {
      a0 = a1 = a2 = 0.f;
    } else {
      a0 = okT ? xb[(size_t)((y - 1) * 64 + x0 - 1) * CC] : 0.f;
      a1 = xb[(size_t)(y * 64 + x0 - 1) * CC];
      a2 = okB ? xb[(size_t)((y + 1) * 64 + x0 - 1) * CC] : 0.f;
    }
    b0 = okT ? xb[(size_t)((y - 1) * 64 + x0) * CC] : 0.f;
    b1 = xb[(size_t)(y * 64 + x0) * CC];
    b2 = okB ? xb[(size_t)((y + 1) * 64 + x0) * CC] : 0.f;
    ushort* ob = q1b + ((size_t)b * NN + y * 64) * CC + c;
#pragma unroll 8
    for (int xx = x0; xx < x0 + 8; ++xx) {
      float c0v, c1v, c2v;
      if (xx < 63) {
        c0v = okT ? xb[(size_t)((y - 1) * 64 + xx + 1) * CC] : 0.f;
        c1v = xb[(size_t)(y * 64 + xx + 1) * CC];
        c2v = okB ? xb[(size_t)((y + 1) * 64 + xx + 1) * CC] : 0.f;
      } else {
        c0v = c1v = c2v = 0.f;
      }
      float acc = bi;
      acc += a0 * wr[0] + b0 * wr[1] + c0v * wr[2];
      acc += a1 * wr[3] + b1 * wr[4] + c1v * wr[5];
      acc += a2 * wr[6] + b2 * wr[7] + c2v * wr[8];
      ob[(size_t)xx * CC] = f2bf(acc);
      a0 = b0; a1 = b1; a2 = b2;
      b0 = c0v; b1 = c1v; b2 = c2v;
    }
  } else if (bid < 6208) {
    int i0 = (bid - 6144) * 1024 + c * 4;
    float4 v = *(const float4*)&pw_w[i0];
    ushort tmp[4] = {f2bf(v.x), f2bf(v.y), f2bf(v.z), f2bf(v.w)};
    *(uint2*)&pwB[i0] = *(uint2*)tmp;
  } else if (bid < 6336) {
    int i0 = (bid - 6208) * 1024 + c * 4;
    float4 v = *(const float4*)&kv_w[i0];
    ushort tmp[4] = {f2bf(v.x), f2bf(v.y), f2bf(v.z), f2bf(v.w)};
    *(uint2*)&kvB[i0] = *(uint2*)tmp;
  } else {
    int i0 = (bid - 6336) * 1024 + c * 4;
    float4 v = *(const float4*)&proj_w[i0];
    float vv[4] = {v.x, v.y, v.z, v.w};
    ushort th[4], tl[4];
#pragma unroll
    for (int j = 0; j < 4; ++j) {
      th[j] = f2bf(vv[j]);
      tl[j] = f2bf(vv[j] - bf2f(th[j]));
    }
    *(uint2*)&pjH[i0] = *(uint2*)th;
    *(uint2*)&pjL[i0] = *(uint2*)tl;
  }
}

// ---------------------------------------------------------------------------
// 2) FUSED q-GEMM + kv-GEMM. 64x64 tiles, double-buffered single-barrier.
//    NEW: depth-2 register pipeline — at iter i we store the set loaded at
//    iter i-1 (loads long returned -> no vmcnt stall at the LDS store) and
//    issue loads for stage i+2. Loop fully unrolled so set indices are
//    compile-time (rule: runtime-indexed ext_vector arrays spill).
__global__ __launch_bounds__(256) void gemm_qkv(
    const ushort* __restrict__ q1b, const ushort* __restrict__ xsr,
    const ushort* __restrict__ pwB, const float* __restrict__ pw_b,
    const ushort* __restrict__ kvB, const float* __restrict__ kv_b,
    ushort* __restrict__ qB, ushort* __restrict__ kB,
    ushort* __restrict__ vT) {
  __shared__ ushort smem[2][128 * 40];
  int bid = blockIdx.x;
  bool is0 = bid < 1024;
  const ushort* A;
  const ushort* W;
  const float* bias;
  int r0, c0;
  if (is0) {
    A = q1b; W = pwB; bias = pw_b;
    r0 = (bid >> 2) * 64; c0 = (bid & 3) * 64;
  } else {
    int sid = bid - 1024;
    A = xsr; W = kvB; bias = kv_b;
    r0 = (sid >> 3) * 64; c0 = (sid & 7) * 64;
  }
  const bool vmode = (!is0) && (c0 >= 256);

  int t = threadIdx.x;
  int lane = t & 63, w = t >> 6;
  int l31 = lane & 31, half = lane >> 5;
  int wr = w >> 1, wc = w & 1;
  int rowA = t >> 2, kq = (t & 3) * 8;

  f32x16 acc;
#pragma unroll
  for (int i = 0; i < 16; ++i) acc[i] = 0.f;

  short8 ra[2], rw[2];
  auto prefetch = [&](int kc, int s) {
    ra[s] = *(const short8*)&A[(size_t)(r0 + rowA) * 256 + kc + kq];
    rw[s] = *(const short8*)&W[(size_t)(c0 + rowA) * 256 + kc + kq];
  };
  auto store = [&](ushort* buf, int s) {
    *(short8*)&buf[rowA * 40 + kq] = ra[s];
    *(short8*)&buf[64 * 40 + rowA * 40 + kq] = rw[s];
  };

  prefetch(0, 0);
  store(smem[0], 0);
  prefetch(32, 1);
  __syncthreads();
#pragma unroll
  for (int i = 0; i < 8; ++i) {
    ushort* cur = smem[i & 1];
    ushort* nxt = smem[(i & 1) ^ 1];
    if (i < 7) store(nxt, (i + 1) & 1);       // set loaded >=1 iter ago
    if (i < 6) prefetch((i + 2) * 32, i & 1); // depth-2 issue
#pragma unroll
    for (int ks = 0; ks < 2; ++ks) {
      short8 af = *(const short8*)&cur[(wr * 32 + l31) * 40 + ks * 16 + half * 8];
      short8 wf = *(const short8*)&cur[64 * 40 + (wc * 32 + l31) * 40 + ks * 16 + half * 8];
      if (vmode)
        acc = __builtin_amdgcn_mfma_f32_32x32x16_bf16(wf, af, acc, 0, 0, 0);
      else
        acc = __builtin_amdgcn_mfma_f32_32x32x16_bf16(af, wf, acc, 0, 0, 0);
    }
    __syncthreads();
  }

#pragma unroll
  for (int i = 0; i < 16; ++i) {
    int rl = (i & 3) + 8 * (i >> 2) + 4 * half;
    if (is0) {
      int r = r0 + wr * 32 + rl;
      int c = c0 + wc * 32 + l31;
      int b = r >> 12, n = r & 4095;
      int h = c >> 5, d = c & 31;
      qB[((size_t)(b * 8 + h) * NN + n) * 32 + d] =
          f2bf((acc[i] + bias[c]) * SLF);
    } else if (!vmode) {
      int r = r0 + wr * 32 + rl;
      int c = c0 + wc * 32 + l31;
      int b = r >> 10, m = r & 1023;
      int h = c >> 5, d = c & 31;
      kB[((size_t)(b * 8 + h) * MM + m) * 32 + d] = f2bf(acc[i] + bias[c]);
    } else {
      int c = c0 + wc * 32 + rl;
      int r = r0 + wr * 32 + l31;
      int b = r >> 10, m = r & 1023;
      int cv = c - 256;
      int h = cv >> 5, d = cv & 31;
      vT[((size_t)(b * 8 + h) * 32 + d) * MM + m] = f2bf(acc[i] + bias[c]);
    }
  }
}

// ---------------------------------------------------------------------------
// 3) MFMA flash attention, staged K/V, setprio, f32-shuffle denominator.
//    NEW: depth-2 register pipeline for K/V staging — iter mc stores the
//    set loaded at iter mc-1 (vmcnt-free) and issues loads for chunk mc+2.
//    Loop unrolled x2 so register-set indices (mc&1) are compile-time.
__global__ __launch_bounds__(256, 4) void attn_mfma(
    const ushort* __restrict__ qB, const ushort* __restrict__ kB,
    const ushort* __restrict__ vT, ushort* __restrict__ aH,
    ushort* __restrict__ aL) {
  __shared__ ushort sKa[2][8][264];
  __shared__ ushort sVa[2][8][264];
  __shared__ ushort pB[4][4][512];
  int t = threadIdx.x;
  int lane = t & 63, w = t >> 6;
  int l31 = lane & 31, half = lane >> 5;
  int bh = blockIdx.x;
  int b = bh >> 3, h = bh & 7;
  int q0 = blockIdx.y * 128;

  const ushort* qrow = qB + ((size_t)bh * NN + q0 + w * 32 + l31) * 32;
  short8 bq0 = *(const short8*)(qrow + half * 8);
  short8 bq1 = *(const short8*)(qrow + 16 + half * 8);

  const ushort* kbase = kB + (size_t)bh * MM * 32;
  const ushort* vbase = vT + (size_t)bh * 32 * MM;
  int krow = t >> 2, kq = (t & 3) * 8;
  int vd = t >> 3, vmo = (t & 7) * 8;
  int kreg_idx = (krow >> 5) * 4 + (kq >> 4) * 2 + ((kq >> 3) & 1);
  int klane = (krow & 31) * 8;
  int vreg_idx = (vmo >> 4) * 2 + ((vmo >> 3) & 1);
  int vlane = vd * 8;

  // set s holds chunk c with (c & 1) == s
  short8 kr[2], vr[2];
  kr[0] = *(const short8*)&kbase[(size_t)krow * 32 + kq];
  vr[0] = *(const short8*)&vbase[(size_t)vd * MM + vmo];
  kr[1] = *(const short8*)&kbase[(size_t)(64 + krow) * 32 + kq];
  vr[1] = *(const short8*)&vbase[(size_t)vd * MM + 64 + vmo];
  *(short8*)&sKa[0][kreg_idx][klane] = kr[0];
  *(short8*)&sVa[0][vreg_idx][vlane] = vr[0];

  f32x16 o;
#pragma unroll
  for (int i = 0; i < 16; ++i) o[i] = 0.f;
  float psum = 0.f;
  __syncthreads();

#pragma unroll 2
  for (int mc = 0; mc < 16; ++mc) {
    int cur = mc & 1, nxt = cur ^ 1;

    // S^T = K·Q^T : two 32x32 tiles
    f32x16 st[2];
    __builtin_amdgcn_s_setprio(1);
#pragma unroll
    for (int tt = 0; tt < 2; ++tt) {
      short8 a0 = *(const short8*)&sKa[cur][tt * 4 + 0 + half][l31 * 8];
      short8 a1 = *(const short8*)&sKa[cur][tt * 4 + 2 + half][l31 * 8];
      f32x16 z;
#pragma unroll
      for (int i = 0; i < 16; ++i) z[i] = 0.f;
      z = __builtin_amdgcn_mfma_f32_32x32x16_bf16(a0, bq0, z, 0, 0, 0);
      z = __builtin_amdgcn_mfma_f32_32x32x16_bf16(a1, bq1, z, 0, 0, 0);
      st[tt] = z;
    }
    __builtin_amdgcn_s_setprio(0);

    // Store chunk mc+1 (loaded last iter -> vmcnt-free) into buffer nxt;
    // issue loads for chunk mc+2 into the set just freed (== cur set).
    if (mc < 15) {
      *(short8*)&sKa[nxt][kreg_idx][klane] = kr[nxt];
      *(short8*)&sVa[nxt][vreg_idx][vlane] = vr[nxt];
    }
    if (mc < 14) {
      int m2 = (mc + 2) * 64;
      kr[cur] = *(const short8*)&kbase[(size_t)(m2 + krow) * 32 + kq];
      vr[cur] = *(const short8*)&vbase[(size_t)vd * MM + m2 + vmo];
    }

    // P = exp2(st), bf16-truncated, frag-major store; f32 row-sum folded in.
#pragma unroll
    for (int tt = 0; tt < 2; ++tt) {
#pragma unroll
      for (int rg = 0; rg < 4; ++rg) {
        float p0 = EXP2F(st[tt][rg * 4 + 0]);
        float p1 = EXP2F(st[tt][rg * 4 + 1]);
        float p2 = EXP2F(st[tt][rg * 4 + 2]);
        float p3 = EXP2F(st[tt][rg * 4 + 3]);
        psum += (p0 + p1) + (p2 + p3);
        uint2 pk;
        pk.x = __builtin_amdgcn_perm(__builtin_bit_cast(unsigned, p1),
                                     __builtin_bit_cast(unsigned, p0), 0x07060302);
        pk.y = __builtin_amdgcn_perm(__builtin_bit_cast(unsigned, p3),
                                     __builtin_bit_cast(unsigned, p2), 0x07060302);
        *(uint2*)&pB[w][2 * tt + (rg >> 1)][((rg & 1) * 32 + l31) * 8 + 4 * half] = pk;
      }
    }

    // O^T += V^T·P
    __builtin_amdgcn_s_setprio(1);
#pragma unroll
    for (int kb = 0; kb < 4; ++kb) {
      short8 av = *(const short8*)&sVa[cur][kb * 2 + half][l31 * 8];
      short8 bp = *(const short8*)&pB[w][kb][lane * 8];
      o = __builtin_amdgcn_mfma_f32_32x32x16_bf16(av, bp, o, 0, 0, 0);
    }
    __builtin_amdgcn_s_setprio(0);

    __syncthreads();
  }

  float denom = psum + __shfl_xor(psum, 32);
  float inv = 1.f / denom;
  size_t rbase = ((size_t)b * NN + q0 + w * 32 + l31) * 256 + h * 32;
#pragma unroll
  for (int rg = 0; rg < 4; ++rg) {
#pragma unroll
    for (int j = 0; j < 4; ++j) {
      float v = o[rg * 4 + j] * inv;
      ushort hi = f2bf(v);
      ushort lo = f2bf(v - bf2f(hi));
      int d = rg * 8 + half * 4 + j;
      aH[rbase + d] = hi;
      aL[rbase + d] = lo;
    }
  }
}

// ---------------------------------------------------------------------------
// 4) proj GEMM, hi/lo split on A and W, 64x64 tiles, double-buffered
//    single-barrier. NEW: depth-2 register pipeline (same as gemm_qkv).
__global__ __launch_bounds__(256) void gemm_proj(
    const ushort* __restrict__ A, const ushort* __restrict__ A2,
    const ushort* __restrict__ Whi, const ushort* __restrict__ Wlo,
    const float* __restrict__ bias, float* __restrict__ out) {
  __shared__ ushort smem[2][4 * 64 * 40];
  constexpr int OA = 0, OA2 = 64 * 40, OW = 2 * 64 * 40, OW2 = 3 * 64 * 40;
  int bid = blockIdx.x;
  int r0 = (bid >> 2) * 64, c0 = (bid & 3) * 64;

  int t = threadIdx.x;
  int lane = t & 63, w = t >> 6;
  int l31 = lane & 31, half = lane >> 5;
  int wr = w >> 1, wc = w & 1;
  int rowA = t >> 2, kq = (t & 3) * 8;

  f32x16 acc;
#pragma unroll
  for (int i = 0; i < 16; ++i) acc[i] = 0.f;

  short8 ra[2], ra2[2], rwh[2], rwl[2];
  auto prefetch = [&](int kc, int s) {
    ra[s]  = *(const short8*)&A[(size_t)(r0 + rowA) * 256 + kc + kq];
    ra2[s] = *(const short8*)&A2[(size_t)(r0 + rowA) * 256 + kc + kq];
    rwh[s] = *(const short8*)&Whi[(size_t)(c0 + rowA) * 256 + kc + kq];
    rwl[s] = *(const short8*)&Wlo[(size_t)(c0 + rowA) * 256 + kc + kq];
  };
  auto store = [&](ushort* buf, int s) {
    *(short8*)&buf[OA + rowA * 40 + kq] = ra[s];
    *(short8*)&buf[OA2 + rowA * 40 + kq] = ra2[s];
    *(short8*)&buf[OW + rowA * 40 + kq] = rwh[s];
    *(short8*)&buf[OW2 + rowA * 40 + kq] = rwl[s];
  };

  prefetch(0, 0);
  store(smem[0], 0);
  prefetch(32, 1);
  __syncthreads();
#pragma unroll
  for (int i = 0; i < 8; ++i) {
    ushort* cur = smem[i & 1];
    ushort* nxt = smem[(i & 1) ^ 1];
    if (i < 7) store(nxt, (i + 1) & 1);
    if (i < 6) prefetch((i + 2) * 32, i & 1);
#pragma unroll
    for (int ks = 0; ks < 2; ++ks) {
      int ro = (wr * 32 + l31) * 40 + ks * 16 + half * 8;
      int co = (wc * 32 + l31) * 40 + ks * 16 + half * 8;
      short8 af = *(const short8*)&cur[OA + ro];
      short8 af2 = *(const short8*)&cur[OA2 + ro];
      short8 wf = *(const short8*)&cur[OW + co];
      short8 wf2 = *(const short8*)&cur[OW2 + co];
      acc = __builtin_amdgcn_mfma_f32_32x32x16_bf16(af, wf, acc, 0, 0, 0);
      acc = __builtin_amdgcn_mfma_f32_32x32x16_bf16(af2, wf, acc, 0, 0, 0);
      acc = __builtin_amdgcn_mfma_f32_32x32x16_bf16(af, wf2, acc, 0, 0, 0);
    }
    __syncthreads();
  }

#pragma unroll
  for (int i = 0; i < 16; ++i) {
    int rl = (i & 3) + 8 * (i >> 2) + 4 * half;
    int r = r0 + wr * 32 + rl;
    int c = c0 + wc * 32 + l31;
    out[(size_t)r * 256 + c] = acc[i] + bias[c];
  }
}

// ---------------------------------------------------------------------------
extern "C" void kernel_launch(void* const* d_in, const int* in_sizes, int n_in,
                              void* d_out, int out_size, void* d_ws, size_t ws_size,
                              hipStream_t stream) {
  const float* x      = (const float*)d_in[0];
  const float* dw_w   = (const float*)d_in[1];
  const float* dw_b   = (const float*)d_in[2];
  const float* pw_w   = (const float*)d_in[3];
  const float* pw_b   = (const float*)d_in[4];
  const float* sr_w   = (const float*)d_in[5];
  const float* ln_g   = (const float*)d_in[6];
  const float* ln_b   = (const float*)d_in[7];
  const float* kv_w   = (const float*)d_in[8];
  const float* kv_b   = (const float*)d_in[9];
  const float* proj_w = (const float*)d_in[10];
  const float* proj_b = (const float*)d_in[11];
  float* out = (float*)d_out;

  char* ws = (char*)d_ws;
  ushort* q1b = (ushort*)(ws);                  // 16384x256 bf16  (8 MB)
  ushort* xsr = (ushort*)(ws + (8u << 20));     // 4096x256        (2 MB)
  ushort* qB  = (ushort*)(ws + (16u << 20));    // 32x4096x32      (8 MB)
  ushort* kBp = (ushort*)(ws + (24u << 20));    // 32x1024x32      (2 MB)
  ushort* vTp = (ushort*)(ws + (26u << 20));    // 32x32x1024      (2 MB)
  ushort* aH  = (ushort*)(ws + (28u << 20));    // 16384x256       (8 MB)
  ushort* aL  = (ushort*)(ws + (36u << 20));    // 16384x256       (8 MB)
  ushort* pwB = (ushort*)(ws + (44u << 20));                 // 128 KB
  ushort* kvB = (ushort*)(ws + (44u << 20) + (512u << 10));  // 256 KB
  ushort* pjH = (ushort*)(ws + (45u << 20));                 // 128 KB
  ushort* pjL = (ushort*)(ws + (45u << 20) + (512u << 10));  // 128 KB

  pre_fused<<<dim3(6400), 256, 0, stream>>>(x, dw_w, dw_b, sr_w, ln_g, ln_b,
                                            pw_w, kv_w, proj_w,
                                            q1b, xsr, pwB, kvB, pjH, pjL);
  gemm_qkv<<<dim3(1536), 256, 0, stream>>>(q1b, xsr, pwB, pw_b, kvB, kv_b,
                                           qB, kBp, vTp);
  attn_mfma<<<dim3(32, 32), 256, 0, stream>>>(qB, kBp, vTp, aH, aL);
  gemm_proj<<<dim3(1024), 256, 0, stream>>>(aH, aL, pjH, pjL, proj_b, out);
}